// Round 1
// baseline (282.277 us; speedup 1.0000x reference)
//
#include <hip/hip_runtime.h>

// Problem constants (from reference setup_inputs)
#define BB   32
#define MM   512
#define NN   256
#define HH   128
#define WW   128
#define HWSZ (HH * WW)   // 16384 cells per (b)

// ---------------------------------------------------------------------------
// Fast path: build per-(b,cell) linked lists, then gather (coalesced writes,
// no zero-fill, no output atomics).
// ws layout: head[BB*HWSZ] ints (2 MiB), next[BB*MM] ints (64 KiB)
// ---------------------------------------------------------------------------

__global__ void init_heads_kernel(int* __restrict__ head, int n) {
    int i = blockIdx.x * blockDim.x + threadIdx.x;
    if (i < n) head[i] = -1;
}

__global__ void build_lists_kernel(const int* __restrict__ loc,
                                   int* __restrict__ head,
                                   int* __restrict__ next) {
    int t = blockIdx.x * blockDim.x + threadIdx.x;   // t = b*MM + m
    if (t >= BB * MM) return;
    int b  = t / MM;
    int m  = t - b * MM;
    int y  = loc[2 * t];
    int xx = loc[2 * t + 1];
    int flat = y * WW + xx;
    // push-front: head holds m (per-b index), next indexed by b*MM + m
    next[t] = atomicExch(&head[b * HWSZ + flat], m);
}

__global__ void gather_out_kernel(const float* __restrict__ x,
                                  const int* __restrict__ head,
                                  const int* __restrict__ next,
                                  float* __restrict__ out) {
    // one thread = (b, n, 4 consecutive flat cells)
    int tid = blockIdx.x * blockDim.x + threadIdx.x;   // [0, BB*NN*HWSZ/4)
    const int Q = HWSZ / 4;                             // 4096 quads per (b,n)
    int flatq = tid % Q;
    int rem   = tid / Q;
    int n     = rem % NN;
    int b     = rem / NN;

    const int4 h = *reinterpret_cast<const int4*>(head + b * HWSZ + flatq * 4);

    // x[(b*MM + m)*NN + n]  ->  xb[m*NN]
    const float* xb = x + (size_t)b * MM * NN + n;
    const int*   nb = next + b * MM;

    float4 acc = make_float4(0.f, 0.f, 0.f, 0.f);
    for (int m = h.x; m >= 0; m = nb[m]) acc.x += xb[(size_t)m * NN];
    for (int m = h.y; m >= 0; m = nb[m]) acc.y += xb[(size_t)m * NN];
    for (int m = h.z; m >= 0; m = nb[m]) acc.z += xb[(size_t)m * NN];
    for (int m = h.w; m >= 0; m = nb[m]) acc.w += xb[(size_t)m * NN];

    // out[((b*NN + n) * HWSZ) + flat]  — consecutive threads -> consecutive 16B
    size_t o = ((size_t)(b * NN + n)) * HWSZ + (size_t)flatq * 4;
    *reinterpret_cast<float4*>(out + o) = acc;
}

// ---------------------------------------------------------------------------
// Fallback path (only if ws_size is too small): zero-fill + atomic scatter.
// ---------------------------------------------------------------------------

__global__ void zero_out_kernel(float4* __restrict__ out, int n4) {
    int i = blockIdx.x * blockDim.x + threadIdx.x;
    if (i < n4) out[i] = make_float4(0.f, 0.f, 0.f, 0.f);
}

__global__ void scatter_atomic_kernel(const float* __restrict__ x,
                                      const int* __restrict__ loc,
                                      float* __restrict__ out) {
    int t = blockIdx.x * blockDim.x + threadIdx.x;    // [0, BB*MM*NN)
    if (t >= BB * MM * NN) return;
    int n  = t % NN;
    int bm = t / NN;        // b*MM + m
    int b  = bm / MM;
    int y  = loc[2 * bm];
    int xx = loc[2 * bm + 1];
    int flat = y * WW + xx;
    size_t o = ((size_t)(b * NN + n)) * HWSZ + flat;
    atomicAdd(out + o, x[t]);
}

// ---------------------------------------------------------------------------

extern "C" void kernel_launch(void* const* d_in, const int* in_sizes, int n_in,
                              void* d_out, int out_size, void* d_ws, size_t ws_size,
                              hipStream_t stream) {
    const float* x   = (const float*)d_in[0];
    const int*   loc = (const int*)d_in[1];
    float*       out = (float*)d_out;

    const size_t needed = (size_t)(BB * HWSZ + BB * MM) * sizeof(int);

    if (ws_size >= needed) {
        int* head = (int*)d_ws;
        int* next = head + BB * HWSZ;

        {
            int n = BB * HWSZ;                       // 524288
            init_heads_kernel<<<(n + 255) / 256, 256, 0, stream>>>(head, n);
        }
        {
            int n = BB * MM;                         // 16384
            build_lists_kernel<<<(n + 255) / 256, 256, 0, stream>>>(loc, head, next);
        }
        {
            int n = BB * NN * HWSZ / 4;              // 33,554,432 quads -> 8,388,608 threads
            gather_out_kernel<<<n / 256, 256, 0, stream>>>(x, head, next, out);
        }
    } else {
        {
            int n4 = BB * NN * HWSZ / 4;             // 33,554,432 float4s
            zero_out_kernel<<<(n4 + 255) / 256, 256, 0, stream>>>((float4*)out, n4);
        }
        {
            int n = BB * MM * NN;                    // 4,194,304
            scatter_atomic_kernel<<<(n + 255) / 256, 256, 0, stream>>>(x, loc, out);
        }
    }
}

// Round 2
// 128.164 us; speedup vs baseline: 2.2025x; 2.2025x over previous
//
#include <hip/hip_runtime.h>

// Problem constants (from reference setup_inputs)
#define BB   32
#define MM   512
#define NN   256
#define HH   128
#define WW   128
#define HWSZ (HH * WW)            // 16384 cells per batch

#define CELLS_PER_BLK 512         // flat-cells owned by one block
#define BLKS_PER_B    (HWSZ / CELLS_PER_BLK)   // 32
#define NSPLIT        2           // split n-range across blocks for occupancy
#define NCHUNK        (NN / NSPLIT)            // 128 n-values per block
#define KCAP          8           // per-thread private entity capacity (2 cells)

// One block = (b, 512 cells, 128 n). 256 threads; thread t owns cells
// F0+2t, F0+2t+1. Phase 1: scan the batch's 512 entities, keep the ~16 that
// land in this block's cell range (LDS). Phase 2: distribute to per-thread
// registers (compile-time-indexed). Phase 3: stream over n, accumulating
// float4 x-rows and storing float2 per n — every output element written
// exactly once, fully coalesced (2 KiB contiguous per block per n).
__global__ __launch_bounds__(256)
void scatter_stream_kernel(const float* __restrict__ x,
                           const int*   __restrict__ loc,
                           float*       __restrict__ out) {
    __shared__ int s_m[MM];
    __shared__ int s_c[MM];
    __shared__ int s_cnt;

    const int t    = threadIdx.x;                       // 0..255
    const int blk  = blockIdx.x;                        // 0..2047
    const int b    = blk / (BLKS_PER_B * NSPLIT);
    const int rem  = blk % (BLKS_PER_B * NSPLIT);
    const int sub  = rem / NSPLIT;
    const int half = rem % NSPLIT;
    const int F0   = sub * CELLS_PER_BLK;
    const int n_lo = half * NCHUNK;

    if (t == 0) s_cnt = 0;
    __syncthreads();

    // ---- Phase 1: scan this batch's entities, keep ones in [F0, F0+512) ----
    const int* lb = loc + b * MM * 2;
    #pragma unroll
    for (int i = 0; i < 2; ++i) {
        const int m  = t + i * 256;
        const int y  = lb[2 * m];
        const int xx = lb[2 * m + 1];
        const int c  = y * WW + xx - F0;
        if ((unsigned)c < (unsigned)CELLS_PER_BLK) {
            const int idx = atomicAdd(&s_cnt, 1);
            s_m[idx] = m;
            s_c[idx] = c;
        }
    }
    __syncthreads();
    const int cnt = s_cnt;                              // avg ~16, max 512

    // ---- Phase 2: per-thread private list for cells (2t, 2t+1) ----
    int pk[KCAP];                                        // (m<<1)|which — static-indexed only
    #pragma unroll
    for (int k = 0; k < KCAP; ++k) pk[k] = 0;
    int myCnt = 0;
    for (int e = 0; e < cnt; ++e) {
        const int c = s_c[e];
        if ((c >> 1) == t) {
            const int v = (s_m[e] << 1) | (c & 1);
            #pragma unroll
            for (int k = 0; k < KCAP; ++k)
                if (myCnt == k) pk[k] = v;               // compile-time index
            ++myCnt;
        }
    }
    const bool ovf = (myCnt > KCAP);                     // ~P(1e-11): LDS-rescan path
    if (ovf) myCnt = 0;                                  // slow path recomputes fully

    // wave-uniform trip count
    int wmax = myCnt;
    #pragma unroll
    for (int s = 1; s < 64; s <<= 1)
        wmax = max(wmax, __shfl_xor(wmax, s));
    wmax = __builtin_amdgcn_readfirstlane(wmax);
    const bool ovfAny = (__ballot(ovf) != 0ull);         // wave-uniform

    // ---- Phase 3: stream over n ----
    const float* xb = x + (size_t)b * MM * NN;           // + m*NN + n
    float* ob = out + (size_t)b * NN * HWSZ + (size_t)n_lo * HWSZ + F0 + 2 * t;

    if (!ovfAny) {
        for (int n0 = 0; n0 < NCHUNK; n0 += 4) {
            float a0x = 0.f, a0y = 0.f, a0z = 0.f, a0w = 0.f;
            float a1x = 0.f, a1y = 0.f, a1z = 0.f, a1w = 0.f;
            #pragma unroll
            for (int k = 0; k < KCAP; ++k) {
                if (k >= wmax) break;                    // wave-uniform break
                if (k < myCnt) {
                    const int m = pk[k] >> 1;
                    const float4 xv =
                        *reinterpret_cast<const float4*>(xb + (size_t)m * NN + n_lo + n0);
                    if (pk[k] & 1) { a1x += xv.x; a1y += xv.y; a1z += xv.z; a1w += xv.w; }
                    else           { a0x += xv.x; a0y += xv.y; a0z += xv.z; a0w += xv.w; }
                }
            }
            float* op = ob + (size_t)n0 * HWSZ;
            *reinterpret_cast<float2*>(op)                    = make_float2(a0x, a1x);
            *reinterpret_cast<float2*>(op + (size_t)HWSZ)     = make_float2(a0y, a1y);
            *reinterpret_cast<float2*>(op + (size_t)2 * HWSZ) = make_float2(a0z, a1z);
            *reinterpret_cast<float2*>(op + (size_t)3 * HWSZ) = make_float2(a0w, a1w);
        }
    } else {
        // bulletproof fallback: rescan LDS list each iteration (never taken for
        // this input distribution; wave-uniform branch)
        for (int n0 = 0; n0 < NCHUNK; n0 += 4) {
            float a0x = 0.f, a0y = 0.f, a0z = 0.f, a0w = 0.f;
            float a1x = 0.f, a1y = 0.f, a1z = 0.f, a1w = 0.f;
            for (int e = 0; e < cnt; ++e) {
                const int c = s_c[e];
                if ((c >> 1) == t) {
                    const float4 xv = *reinterpret_cast<const float4*>(
                        xb + (size_t)s_m[e] * NN + n_lo + n0);
                    if (c & 1) { a1x += xv.x; a1y += xv.y; a1z += xv.z; a1w += xv.w; }
                    else       { a0x += xv.x; a0y += xv.y; a0z += xv.z; a0w += xv.w; }
                }
            }
            float* op = ob + (size_t)n0 * HWSZ;
            *reinterpret_cast<float2*>(op)                    = make_float2(a0x, a1x);
            *reinterpret_cast<float2*>(op + (size_t)HWSZ)     = make_float2(a0y, a1y);
            *reinterpret_cast<float2*>(op + (size_t)2 * HWSZ) = make_float2(a0z, a1z);
            *reinterpret_cast<float2*>(op + (size_t)3 * HWSZ) = make_float2(a0w, a1w);
        }
    }
}

extern "C" void kernel_launch(void* const* d_in, const int* in_sizes, int n_in,
                              void* d_out, int out_size, void* d_ws, size_t ws_size,
                              hipStream_t stream) {
    const float* x   = (const float*)d_in[0];
    const int*   loc = (const int*)d_in[1];
    float*       out = (float*)d_out;

    const int nblk = BB * BLKS_PER_B * NSPLIT;           // 2048 blocks
    scatter_stream_kernel<<<nblk, 256, 0, stream>>>(x, loc, out);
}

// Round 3
// 122.129 us; speedup vs baseline: 2.3113x; 1.0494x over previous
//
#include <hip/hip_runtime.h>

// Problem constants (from reference setup_inputs)
#define BB   32
#define MM   512
#define NN   256
#define HH   128
#define WW   128
#define HWSZ (HH * WW)            // 16384 cells per batch

#define CELLS_PER_BLK 1024        // flat-cells owned by one block (4 per thread)
#define BLKS_PER_B    (HWSZ / CELLS_PER_BLK)   // 16
#define NSPLIT        4           // split n-range across blocks
#define NCHUNK        (NN / NSPLIT)            // 64 n-values per block
#define KCAP          8           // per-thread private entity capacity (4 cells)

// One block = (b, 1024 cells, 64 n). 256 threads; thread t owns cells
// F0+4t .. F0+4t+3. Phase 1: scan the batch's 512 entities, keep the ~32 that
// land in this block's cell range (LDS). Phase 2: distribute to per-thread
// registers (compile-time-indexed). Phase 3: stream over n in groups of 4,
// accumulating a 4x4 (cell x n) register tile and storing one float4 per n —
// every output element written exactly once, 4 KiB contiguous per block per n.
__global__ __launch_bounds__(256)
void scatter_stream_kernel(const float* __restrict__ x,
                           const int*   __restrict__ loc,
                           float*       __restrict__ out) {
    __shared__ int s_m[MM];
    __shared__ int s_c[MM];
    __shared__ int s_cnt;

    const int t    = threadIdx.x;                       // 0..255
    const int blk  = blockIdx.x;                        // 0..2047
    const int b    = blk / (BLKS_PER_B * NSPLIT);
    const int rem  = blk % (BLKS_PER_B * NSPLIT);
    const int sub  = rem / NSPLIT;
    const int half = rem % NSPLIT;
    const int F0   = sub * CELLS_PER_BLK;
    const int n_lo = half * NCHUNK;

    if (t == 0) s_cnt = 0;
    __syncthreads();

    // ---- Phase 1: scan this batch's entities, keep ones in [F0, F0+1024) ----
    const int* lb = loc + b * MM * 2;
    #pragma unroll
    for (int i = 0; i < 2; ++i) {
        const int m  = t + i * 256;
        const int y  = lb[2 * m];
        const int xx = lb[2 * m + 1];
        const int c  = y * WW + xx - F0;
        if ((unsigned)c < (unsigned)CELLS_PER_BLK) {
            const int idx = atomicAdd(&s_cnt, 1);
            s_m[idx] = m;
            s_c[idx] = c;
        }
    }
    __syncthreads();
    const int cnt = s_cnt;                              // avg ~32, max 512

    // ---- Phase 2: per-thread private list for cells 4t..4t+3 ----
    int pk[KCAP];                                        // (m<<2)|slot — static-indexed only
    #pragma unroll
    for (int k = 0; k < KCAP; ++k) pk[k] = 0;
    int myCnt = 0;
    for (int e = 0; e < cnt; ++e) {
        const int c = s_c[e];
        if ((c >> 2) == t) {
            const int v = (s_m[e] << 2) | (c & 3);
            #pragma unroll
            for (int k = 0; k < KCAP; ++k)
                if (myCnt == k) pk[k] = v;               // compile-time index
            ++myCnt;
        }
    }
    const bool ovf = (myCnt > KCAP);                     // ~P(1e-13): LDS-rescan path
    if (ovf) myCnt = 0;

    // wave-uniform trip count
    int wmax = myCnt;
    #pragma unroll
    for (int s = 1; s < 64; s <<= 1)
        wmax = max(wmax, __shfl_xor(wmax, s));
    wmax = __builtin_amdgcn_readfirstlane(wmax);
    const bool ovfAny = (__ballot(ovf) != 0ull);         // wave-uniform

    // ---- Phase 3: stream over n in groups of 4 ----
    const float* xb = x + (size_t)b * MM * NN + n_lo;    // + m*NN + n0
    float* ob = out + (size_t)b * NN * HWSZ + (size_t)n_lo * HWSZ + F0 + 4 * t;

    if (!ovfAny) {
        for (int n0 = 0; n0 < NCHUNK; n0 += 4) {
            float4 a0 = make_float4(0.f, 0.f, 0.f, 0.f);  // n-offset 0, cells 0..3
            float4 a1 = make_float4(0.f, 0.f, 0.f, 0.f);  // n-offset 1
            float4 a2 = make_float4(0.f, 0.f, 0.f, 0.f);  // n-offset 2
            float4 a3 = make_float4(0.f, 0.f, 0.f, 0.f);  // n-offset 3
            #pragma unroll
            for (int k = 0; k < KCAP; ++k) {
                if (k >= wmax) break;                    // wave-uniform break
                if (k < myCnt) {
                    const int m = pk[k] >> 2;
                    const float4 xv =
                        *reinterpret_cast<const float4*>(xb + (size_t)m * NN + n0);
                    switch (pk[k] & 3) {
                        case 0: a0.x += xv.x; a1.x += xv.y; a2.x += xv.z; a3.x += xv.w; break;
                        case 1: a0.y += xv.x; a1.y += xv.y; a2.y += xv.z; a3.y += xv.w; break;
                        case 2: a0.z += xv.x; a1.z += xv.y; a2.z += xv.z; a3.z += xv.w; break;
                        default:a0.w += xv.x; a1.w += xv.y; a2.w += xv.z; a3.w += xv.w; break;
                    }
                }
            }
            float* op = ob + (size_t)n0 * HWSZ;
            *reinterpret_cast<float4*>(op)                    = a0;
            *reinterpret_cast<float4*>(op + (size_t)HWSZ)     = a1;
            *reinterpret_cast<float4*>(op + (size_t)2 * HWSZ) = a2;
            *reinterpret_cast<float4*>(op + (size_t)3 * HWSZ) = a3;
        }
    } else {
        // bulletproof fallback: rescan LDS list each n-group (never taken for
        // this input distribution; wave-uniform branch)
        for (int n0 = 0; n0 < NCHUNK; n0 += 4) {
            float4 a0 = make_float4(0.f, 0.f, 0.f, 0.f);
            float4 a1 = make_float4(0.f, 0.f, 0.f, 0.f);
            float4 a2 = make_float4(0.f, 0.f, 0.f, 0.f);
            float4 a3 = make_float4(0.f, 0.f, 0.f, 0.f);
            for (int e = 0; e < cnt; ++e) {
                const int c = s_c[e];
                if ((c >> 2) == t) {
                    const float4 xv = *reinterpret_cast<const float4*>(
                        xb + (size_t)s_m[e] * NN + n0);
                    switch (c & 3) {
                        case 0: a0.x += xv.x; a1.x += xv.y; a2.x += xv.z; a3.x += xv.w; break;
                        case 1: a0.y += xv.x; a1.y += xv.y; a2.y += xv.z; a3.y += xv.w; break;
                        case 2: a0.z += xv.x; a1.z += xv.y; a2.z += xv.z; a3.z += xv.w; break;
                        default:a0.w += xv.x; a1.w += xv.y; a2.w += xv.z; a3.w += xv.w; break;
                    }
                }
            }
            float* op = ob + (size_t)n0 * HWSZ;
            *reinterpret_cast<float4*>(op)                    = a0;
            *reinterpret_cast<float4*>(op + (size_t)HWSZ)     = a1;
            *reinterpret_cast<float4*>(op + (size_t)2 * HWSZ) = a2;
            *reinterpret_cast<float4*>(op + (size_t)3 * HWSZ) = a3;
        }
    }
}

extern "C" void kernel_launch(void* const* d_in, const int* in_sizes, int n_in,
                              void* d_out, int out_size, void* d_ws, size_t ws_size,
                              hipStream_t stream) {
    const float* x   = (const float*)d_in[0];
    const int*   loc = (const int*)d_in[1];
    float*       out = (float*)d_out;

    const int nblk = BB * BLKS_PER_B * NSPLIT;           // 2048 blocks
    scatter_stream_kernel<<<nblk, 256, 0, stream>>>(x, loc, out);
}

// Round 5
// 111.137 us; speedup vs baseline: 2.5399x; 1.0989x over previous
//
#include <hip/hip_runtime.h>

// Problem constants (from reference setup_inputs)
#define BB   32
#define MM   512
#define NN   256
#define HH   128
#define WW   128
#define HWSZ (HH * WW)            // 16384 cells per batch

#define CELLS_PER_BLK 1024        // flat-cells owned by one block (4 per thread)
#define BLKS_PER_B    (HWSZ / CELLS_PER_BLK)   // 16
#define NSPLIT        2           // split n-range across blocks
#define NCHUNK        (NN / NSPLIT)            // 128 n-values per block
#define KCAP          8           // per-thread private entity capacity (4 cells)

typedef float f32x4 __attribute__((ext_vector_type(4)));

// One block = (b, 1024 cells, 128 n). 256 threads; thread t owns cells
// F0+4t .. F0+4t+3. Phase 1: scan the batch's 512 entities, keep the ~32 that
// land in this block's cell range (LDS). Phase 2: distribute to per-thread
// registers (compile-time-indexed). Phase 3: stream over n in groups of 4,
// accumulating a 4x4 (cell x n) register tile and storing one nontemporal
// 16B store per n — every output element written exactly once, evict-first so
// the 537 MB write stream doesn't churn L2.
__global__ __launch_bounds__(256)
void scatter_stream_kernel(const float* __restrict__ x,
                           const int*   __restrict__ loc,
                           float*       __restrict__ out) {
    __shared__ int s_m[MM];
    __shared__ int s_c[MM];
    __shared__ int s_cnt;

    const int t    = threadIdx.x;                       // 0..255
    const int blk  = blockIdx.x;                        // 0..1023
    const int b    = blk / (BLKS_PER_B * NSPLIT);
    const int rem  = blk % (BLKS_PER_B * NSPLIT);
    const int sub  = rem / NSPLIT;
    const int half = rem % NSPLIT;
    const int F0   = sub * CELLS_PER_BLK;
    const int n_lo = half * NCHUNK;

    if (t == 0) s_cnt = 0;
    __syncthreads();

    // ---- Phase 1: scan this batch's entities, keep ones in [F0, F0+1024) ----
    const int* lb = loc + b * MM * 2;
    #pragma unroll
    for (int i = 0; i < 2; ++i) {
        const int m  = t + i * 256;
        const int2 yx = *reinterpret_cast<const int2*>(lb + 2 * m);
        const int c  = yx.x * WW + yx.y - F0;
        if ((unsigned)c < (unsigned)CELLS_PER_BLK) {
            const int idx = atomicAdd(&s_cnt, 1);
            s_m[idx] = m;
            s_c[idx] = c;
        }
    }
    __syncthreads();
    const int cnt = s_cnt;                              // avg ~32, max 512

    // ---- Phase 2: per-thread private list for cells 4t..4t+3 ----
    int pk[KCAP];                                        // (m<<2)|slot — static-indexed only
    #pragma unroll
    for (int k = 0; k < KCAP; ++k) pk[k] = 0;
    int myCnt = 0;
    for (int e = 0; e < cnt; ++e) {
        const int c = s_c[e];
        if ((c >> 2) == t) {
            const int v = (s_m[e] << 2) | (c & 3);
            #pragma unroll
            for (int k = 0; k < KCAP; ++k)
                if (myCnt == k) pk[k] = v;               // compile-time index
            ++myCnt;
        }
    }
    const bool ovf = (myCnt > KCAP);                     // ~P(1e-13): LDS-rescan path
    if (ovf) myCnt = 0;

    // wave-uniform trip count
    int wmax = myCnt;
    #pragma unroll
    for (int s = 1; s < 64; s <<= 1)
        wmax = max(wmax, __shfl_xor(wmax, s));
    wmax = __builtin_amdgcn_readfirstlane(wmax);
    const bool ovfAny = (__ballot(ovf) != 0ull);         // wave-uniform

    // ---- Phase 3: stream over n in groups of 4 ----
    const float* xb = x + (size_t)b * MM * NN + n_lo;    // + m*NN + n0
    float* ob = out + (size_t)b * NN * HWSZ + (size_t)n_lo * HWSZ + F0 + 4 * t;

    if (!ovfAny) {
        for (int n0 = 0; n0 < NCHUNK; n0 += 4) {
            f32x4 a0 = {0.f, 0.f, 0.f, 0.f};             // n-offset 0, cells 0..3
            f32x4 a1 = {0.f, 0.f, 0.f, 0.f};             // n-offset 1
            f32x4 a2 = {0.f, 0.f, 0.f, 0.f};             // n-offset 2
            f32x4 a3 = {0.f, 0.f, 0.f, 0.f};             // n-offset 3
            #pragma unroll
            for (int k = 0; k < KCAP; ++k) {
                if (k >= wmax) break;                    // wave-uniform break
                if (k < myCnt) {
                    const int m = pk[k] >> 2;
                    const f32x4 xv =
                        *reinterpret_cast<const f32x4*>(xb + (size_t)m * NN + n0);
                    switch (pk[k] & 3) {
                        case 0: a0.x += xv.x; a1.x += xv.y; a2.x += xv.z; a3.x += xv.w; break;
                        case 1: a0.y += xv.x; a1.y += xv.y; a2.y += xv.z; a3.y += xv.w; break;
                        case 2: a0.z += xv.x; a1.z += xv.y; a2.z += xv.z; a3.z += xv.w; break;
                        default:a0.w += xv.x; a1.w += xv.y; a2.w += xv.z; a3.w += xv.w; break;
                    }
                }
            }
            float* op = ob + (size_t)n0 * HWSZ;
            __builtin_nontemporal_store(a0, reinterpret_cast<f32x4*>(op));
            __builtin_nontemporal_store(a1, reinterpret_cast<f32x4*>(op + (size_t)HWSZ));
            __builtin_nontemporal_store(a2, reinterpret_cast<f32x4*>(op + (size_t)2 * HWSZ));
            __builtin_nontemporal_store(a3, reinterpret_cast<f32x4*>(op + (size_t)3 * HWSZ));
        }
    } else {
        // bulletproof fallback: rescan LDS list each n-group (never taken for
        // this input distribution; wave-uniform branch)
        for (int n0 = 0; n0 < NCHUNK; n0 += 4) {
            f32x4 a0 = {0.f, 0.f, 0.f, 0.f};
            f32x4 a1 = {0.f, 0.f, 0.f, 0.f};
            f32x4 a2 = {0.f, 0.f, 0.f, 0.f};
            f32x4 a3 = {0.f, 0.f, 0.f, 0.f};
            for (int e = 0; e < cnt; ++e) {
                const int c = s_c[e];
                if ((c >> 2) == t) {
                    const f32x4 xv = *reinterpret_cast<const f32x4*>(
                        xb + (size_t)s_m[e] * NN + n0);
                    switch (c & 3) {
                        case 0: a0.x += xv.x; a1.x += xv.y; a2.x += xv.z; a3.x += xv.w; break;
                        case 1: a0.y += xv.x; a1.y += xv.y; a2.y += xv.z; a3.y += xv.w; break;
                        case 2: a0.z += xv.x; a1.z += xv.y; a2.z += xv.z; a3.z += xv.w; break;
                        default:a0.w += xv.x; a1.w += xv.y; a2.w += xv.z; a3.w += xv.w; break;
                    }
                }
            }
            float* op = ob + (size_t)n0 * HWSZ;
            __builtin_nontemporal_store(a0, reinterpret_cast<f32x4*>(op));
            __builtin_nontemporal_store(a1, reinterpret_cast<f32x4*>(op + (size_t)HWSZ));
            __builtin_nontemporal_store(a2, reinterpret_cast<f32x4*>(op + (size_t)2 * HWSZ));
            __builtin_nontemporal_store(a3, reinterpret_cast<f32x4*>(op + (size_t)3 * HWSZ));
        }
    }
}

extern "C" void kernel_launch(void* const* d_in, const int* in_sizes, int n_in,
                              void* d_out, int out_size, void* d_ws, size_t ws_size,
                              hipStream_t stream) {
    const float* x   = (const float*)d_in[0];
    const int*   loc = (const int*)d_in[1];
    float*       out = (float*)d_out;

    const int nblk = BB * BLKS_PER_B * NSPLIT;           // 1024 blocks
    scatter_stream_kernel<<<nblk, 256, 0, stream>>>(x, loc, out);
}